// Round 1
// baseline (1006.980 us; speedup 1.0000x reference)
//
#include <hip/hip_runtime.h>
#include <hip/hip_bf16.h>

#define NTOK 65536
#define NSEG 512

typedef __attribute__((ext_vector_type(8))) short bf16x8;
typedef __attribute__((ext_vector_type(4))) float f32x4;

// ---- workspace byte offsets (all 256-aligned) ----
constexpr size_t OFF_SC   = 0;                      // f32[65536] score accum (zeroed)
constexpr size_t OFF_ACC  = 262144;                 // f32[16]  (zeroed) 0=hinge 1=nll 2=ediff 3=valid
constexpr size_t OFF_HIST = 262144 + 64;            // int[136] (zeroed) LabA,LabB,PredA,PredB
constexpr size_t ZERO_BYTES = 263168;
constexpr size_t OFF_WBT  = 263168;                 // ushort[589824]  W_w^T in bf16
constexpr size_t OFF_LSUM = OFF_WBT + 1179648;      // f32[589824]  lin_w_top+lin_w_bot
constexpr size_t OFF_BCAT = OFF_LSUM + 2359296;     // f32[768*68]  [cls_w | mat_local^T]
constexpr size_t OFF_C0   = OFF_BCAT + 208896;      // f32[34]
constexpr size_t OFF_CML0 = OFF_C0 + 256;           // f32[34]
constexpr size_t OFF_TD   = OFF_CML0 + 256;         // f32[65536]
constexpr size_t OFF_HEAD = OFF_TD + 262144;        // f32[512*768]
constexpr size_t OFF_XSUM = OFF_HEAD + 1572864;     // f32[512*768]
constexpr size_t OFF_Z    = OFF_XSUM + 1572864;     // f32[512*768]
constexpr size_t OFF_G    = OFF_Z + 1572864;        // f32[512*34]
constexpr size_t OFF_GML  = OFF_G + 69632;          // f32[512*34]
constexpr size_t OFF_PRED = OFF_GML + 69632;        // int[65536]
constexpr size_t OFF_P    = OFF_PRED + 262144;      // f32[65536*68]

__device__ __forceinline__ unsigned short f2bf(float f) {
  union { float f; unsigned int u; } v; v.f = f;
  unsigned int r = v.u + 0x7FFFu + ((v.u >> 16) & 1u);
  return (unsigned short)(r >> 16);
}

// ---------------- K1: weight prep ----------------
__global__ __launch_bounds__(256) void k_prep(
    const float* __restrict__ Ww, const float* __restrict__ linw,
    const float* __restrict__ clsw, const float* __restrict__ matl,
    const float* __restrict__ linb, const float* __restrict__ clsb,
    unsigned short* __restrict__ wbT, float* __restrict__ lsum,
    float* __restrict__ bcat, float* __restrict__ c0, float* __restrict__ cml0) {
  int idx = blockIdx.x * 256 + threadIdx.x;
  if (idx < 589824) {                       // wbT[j][k] = bf16(Ww[k][j])
    int j = idx / 768, k = idx - j * 768;
    wbT[idx] = f2bf(Ww[k * 768 + j]);
  } else if (idx < 1179648) {
    int i = idx - 589824;
    lsum[i] = linw[i] + linw[589824 + i];
  } else if (idx < 1179648 + 52224) {
    int i = idx - 1179648;
    int k = i / 68, t = i - k * 68;
    bcat[i] = (t < 34) ? clsw[k * 34 + t] : matl[(t - 34) * 768 + k];
  } else if (idx < 1179648 + 52224 + 68) {
    int t = idx - (1179648 + 52224);
    if (t < 34) {
      float a = clsb[t];
      for (int h = 0; h < 768; ++h) a += linb[h] * clsw[h * 34 + t];
      c0[t] = a;
    } else {
      int u = t - 34; float a = 0.f;
      for (int h = 0; h < 768; ++h) a += linb[h] * matl[u * 768 + h];
      cml0[u] = a;
    }
  }
}

// ---------------- K2: sc[r] = sum_j tanh(x[r]·W[:,j] + Wb[j]) * vw[j]  (bf16 MFMA) -------
__global__ __launch_bounds__(256) void k_score(
    const float* __restrict__ x, const unsigned short* __restrict__ wbT,
    const float* __restrict__ Wb, const float* __restrict__ vw,
    float* __restrict__ sscore) {
  __shared__ unsigned short As[128 * 40];   // [row][k], LDA=40 (bank-spread pad)
  __shared__ unsigned short Bs[64 * 40];    // [col][k] (transposed)
  int tid = threadIdx.x;
  int lane = tid & 63, wid = tid >> 6;
  int wr = wid >> 1, wc = wid & 1;
  int row0 = blockIdx.x * 128;
  int col0 = blockIdx.y * 64;
  f32x4 acc[4][2] = {};
  int sr = tid >> 1, skq = (tid & 1) * 16;
  int sc = tid >> 2, skq2 = (tid & 3) * 8;
  const float* xsrc = x + (size_t)(row0 + sr) * 768 + skq;
  const unsigned short* bsrc = wbT + (size_t)(col0 + sc) * 768 + skq2;

  for (int kk = 0; kk < 768; kk += 32) {
    float4 f0 = *(const float4*)(xsrc + kk);
    float4 f1 = *(const float4*)(xsrc + kk + 4);
    float4 f2 = *(const float4*)(xsrc + kk + 8);
    float4 f3 = *(const float4*)(xsrc + kk + 12);
    union { unsigned short u[8]; bf16x8 v; } p0, p1;
    p0.u[0] = f2bf(f0.x); p0.u[1] = f2bf(f0.y); p0.u[2] = f2bf(f0.z); p0.u[3] = f2bf(f0.w);
    p0.u[4] = f2bf(f1.x); p0.u[5] = f2bf(f1.y); p0.u[6] = f2bf(f1.z); p0.u[7] = f2bf(f1.w);
    p1.u[0] = f2bf(f2.x); p1.u[1] = f2bf(f2.y); p1.u[2] = f2bf(f2.z); p1.u[3] = f2bf(f2.w);
    p1.u[4] = f2bf(f3.x); p1.u[5] = f2bf(f3.y); p1.u[6] = f2bf(f3.z); p1.u[7] = f2bf(f3.w);
    *(bf16x8*)&As[sr * 40 + skq] = p0.v;
    *(bf16x8*)&As[sr * 40 + skq + 8] = p1.v;
    *(bf16x8*)&Bs[sc * 40 + skq2] = *(const bf16x8*)(bsrc + kk);
    __syncthreads();

    bf16x8 a[4], b[2];
    int koff = (lane >> 4) * 8;
    int arow = wr * 64 + (lane & 15);
    int brow = wc * 32 + (lane & 15);
#pragma unroll
    for (int mi = 0; mi < 4; ++mi) a[mi] = *(const bf16x8*)&As[(arow + mi * 16) * 40 + koff];
#pragma unroll
    for (int ni = 0; ni < 2; ++ni) b[ni] = *(const bf16x8*)&Bs[(brow + ni * 16) * 40 + koff];
#pragma unroll
    for (int mi = 0; mi < 4; ++mi)
#pragma unroll
      for (int ni = 0; ni < 2; ++ni)
        acc[mi][ni] = __builtin_amdgcn_mfma_f32_16x16x32_bf16(a[mi], b[ni], acc[mi][ni], 0, 0, 0);
    __syncthreads();
  }
  // epilogue: tanh(+Wb)*vw, reduce over the 16 cols held by the 16-lane group
  int cbase = col0 + wc * 32 + (lane & 15);
  float wbv[2], vwv[2];
#pragma unroll
  for (int ni = 0; ni < 2; ++ni) { wbv[ni] = Wb[cbase + ni * 16]; vwv[ni] = vw[cbase + ni * 16]; }
  int g4 = lane >> 4;
#pragma unroll
  for (int mi = 0; mi < 4; ++mi) {
#pragma unroll
    for (int reg = 0; reg < 4; ++reg) {
      float v = 0.f;
#pragma unroll
      for (int ni = 0; ni < 2; ++ni) v += tanhf(acc[mi][ni][reg] + wbv[ni]) * vwv[ni];
      v += __shfl_xor(v, 1); v += __shfl_xor(v, 2); v += __shfl_xor(v, 4); v += __shfl_xor(v, 8);
      if ((lane & 15) == 0)
        atomicAdd(&sscore[row0 + wr * 64 + mi * 16 + g4 * 4 + reg], v);
    }
  }
}

// ---------------- K3: softmax over S + head + xsum ----------------
__global__ __launch_bounds__(256) void k_softmax_head(
    const float* __restrict__ x, const float* __restrict__ sscore,
    const float* __restrict__ vb, float* __restrict__ td,
    float* __restrict__ head, float* __restrict__ xsum) {
  int n = blockIdx.x, tid = threadIdx.x;
  __shared__ float buf[128];
  __shared__ float tdl[128];
  float scv = 0.f;
  if (tid < 128) { scv = sscore[n * 128 + tid] + vb[0]; buf[tid] = scv; }
  __syncthreads();
  for (int w = 64; w >= 1; w >>= 1) {
    if (tid < w) buf[tid] = fmaxf(buf[tid], buf[tid + w]);
    __syncthreads();
  }
  float m = buf[0];
  __syncthreads();
  float e = 0.f;
  if (tid < 128) { e = expf(scv - m); buf[tid] = e; }
  __syncthreads();
  for (int w = 64; w >= 1; w >>= 1) {
    if (tid < w) buf[tid] += buf[tid + w];
    __syncthreads();
  }
  float ssum = buf[0];
  if (tid < 128) { float t = e / ssum; tdl[tid] = t; td[n * 128 + tid] = t; }
  __syncthreads();
  float aH0 = 0, aH1 = 0, aH2 = 0, aX0 = 0, aX1 = 0, aX2 = 0;
  const float* xb = x + (size_t)n * 128 * 768;
  for (int s = 0; s < 128; ++s) {
    float t = tdl[s];
    const float* xr = xb + s * 768;
    float v0 = xr[tid], v1 = xr[tid + 256], v2 = xr[tid + 512];
    aH0 = fmaf(t, v0, aH0); aH1 = fmaf(t, v1, aH1); aH2 = fmaf(t, v2, aH2);
    aX0 += v0; aX1 += v1; aX2 += v2;
  }
  head[n * 768 + tid] = aH0; head[n * 768 + tid + 256] = aH1; head[n * 768 + tid + 512] = aH2;
  xsum[n * 768 + tid] = aX0; xsum[n * 768 + tid + 256] = aX1; xsum[n * 768 + tid + 512] = aX2;
}

// ---------------- K4: z = head @ lsum ----------------
__global__ __launch_bounds__(256) void k_zgemm(
    const float* __restrict__ head, const float* __restrict__ lsum, float* __restrict__ z) {
  int n0 = blockIdx.x * 4, tid = threadIdx.x;
  __shared__ float hr[4 * 768];
  for (int i = tid; i < 3072; i += 256) hr[i] = head[n0 * 768 + i];
  __syncthreads();
  float acc[4][3] = {};
  for (int h = 0; h < 768; ++h) {
    float h0 = hr[h], h1 = hr[768 + h], h2 = hr[1536 + h], h3 = hr[2304 + h];
#pragma unroll
    for (int i = 0; i < 3; ++i) {
      float ls = lsum[h * 768 + tid + i * 256];
      acc[0][i] = fmaf(h0, ls, acc[0][i]);
      acc[1][i] = fmaf(h1, ls, acc[1][i]);
      acc[2][i] = fmaf(h2, ls, acc[2][i]);
      acc[3][i] = fmaf(h3, ls, acc[3][i]);
    }
  }
#pragma unroll
  for (int r = 0; r < 4; ++r)
#pragma unroll
    for (int i = 0; i < 3; ++i)
      z[(n0 + r) * 768 + tid + i * 256] = acc[r][i];
}

// ---------------- K5: g = z·cls_w cols, gml = z·mat_local rows ----------------
__global__ __launch_bounds__(128) void k_gproj(
    const float* __restrict__ z, const float* __restrict__ clsw,
    const float* __restrict__ matl, float* __restrict__ g, float* __restrict__ gml) {
  int n = blockIdx.x, tid = threadIdx.x;
  __shared__ float zl[768];
  for (int i = tid; i < 768; i += 128) zl[i] = z[n * 768 + i];
  __syncthreads();
  if (tid < 34) {
    float a = 0.f;
    for (int h = 0; h < 768; ++h) a = fmaf(zl[h], clsw[h * 34 + tid], a);
    g[n * 34 + tid] = a;
  } else if (tid < 68) {
    int t = tid - 34; float a = 0.f;
    for (int h = 0; h < 768; ++h) a = fmaf(zl[h], matl[t * 768 + h], a);
    gml[n * 34 + t] = a;
  }
}

// ---------------- K6: P[r][0:34]=x·cls_w, P[r][34:68]=x·mat_local^T  (f32) -------
__global__ __launch_bounds__(256) void k_pgemm(
    const float* __restrict__ x, const float* __restrict__ bcat, float* __restrict__ P) {
  __shared__ float At[128 * 20];
  __shared__ float Bt[16 * 68];
  int tid = threadIdx.x;
  int row0 = blockIdx.x * 128;
  int q = tid >> 2, cg = tid & 3;          // rows 2q,2q+1 ; cols cg*17..+16
  int sr = tid >> 1, sh = (tid & 1) * 8;   // staging
  float acc0[17] = {}, acc1[17] = {};
  const float* xs = x + (size_t)(row0 + sr) * 768 + sh;
  for (int kk = 0; kk < 768; kk += 16) {
    float4 v0 = *(const float4*)(xs + kk);
    float4 v1 = *(const float4*)(xs + kk + 4);
    *(float4*)&At[sr * 20 + sh] = v0;
    *(float4*)&At[sr * 20 + sh + 4] = v1;
    for (int i = tid; i < 1088; i += 256) Bt[i] = bcat[kk * 68 + i];
    __syncthreads();
    float ar0[16], ar1[16];
#pragma unroll
    for (int t4 = 0; t4 < 4; ++t4) {
      *(float4*)&ar0[t4 * 4] = *(const float4*)&At[(2 * q) * 20 + t4 * 4];
      *(float4*)&ar1[t4 * 4] = *(const float4*)&At[(2 * q + 1) * 20 + t4 * 4];
    }
#pragma unroll
    for (int i = 0; i < 17; ++i) {
      int c = cg * 17 + i;
      float a0 = acc0[i], a1 = acc1[i];
#pragma unroll
      for (int k = 0; k < 16; ++k) {
        float bv = Bt[k * 68 + c];
        a0 = fmaf(ar0[k], bv, a0);
        a1 = fmaf(ar1[k], bv, a1);
      }
      acc0[i] = a0; acc1[i] = a1;
    }
    __syncthreads();
  }
#pragma unroll
  for (int i = 0; i < 17; ++i) {
    P[(size_t)(row0 + 2 * q) * 68 + cg * 17 + i] = acc0[i];
    P[(size_t)(row0 + 2 * q + 1) * 68 + cg * 17 + i] = acc1[i];
  }
}

// ---------------- K7: per-token logits/argmax/hinge/CE/energy-local/outputs -------
__global__ __launch_bounds__(128) void k_final(
    const float* __restrict__ P, const float* __restrict__ td,
    const int* __restrict__ labels, const int* __restrict__ padp,
    const float* __restrict__ g, const float* __restrict__ gml,
    const float* __restrict__ c0, const float* __restrict__ cml0,
    float* __restrict__ out, int* __restrict__ pred,
    float* __restrict__ accs, int* __restrict__ hist) {
  int n = blockIdx.x, s = threadIdx.x;
  int r = n * 128 + s;
  __shared__ float gs[34], gmls[34], c0s[34], cml0s[34];
  __shared__ float rb[128];
  if (s < 34) { gs[s] = g[n * 34 + s]; gmls[s] = gml[n * 34 + s]; c0s[s] = c0[s]; cml0s[s] = cml0[s]; }
  __syncthreads();
  float p[68];
  const float4* prow = (const float4*)(P + (size_t)r * 68);
#pragma unroll
  for (int i = 0; i < 17; ++i) {
    float4 v = prow[i];
    p[i * 4] = v.x; p[i * 4 + 1] = v.y; p[i * 4 + 2] = v.z; p[i * 4 + 3] = v.w;
  }
  float tds = td[r];
  int lab = labels[r];
  int pad = padp[0];
  float lg[34];
#pragma unroll
  for (int t = 0; t < 34; ++t) lg[t] = fmaxf(p[t] + tds * gs[t] + c0s[t], 0.f);
  float best = lg[0]; int pidx = 0;
#pragma unroll
  for (int t = 1; t < 34; ++t) { if (lg[t] > best) { best = lg[t]; pidx = t; } }
  // outputs: logits rows (row r+1; dup first/last), labels
  float* orow = out + 1 + (size_t)(r + 1) * 34;
#pragma unroll
  for (int t = 0; t < 34; ++t) orow[t] = lg[t];
  if (r == 0) {
#pragma unroll
    for (int t = 0; t < 34; ++t) out[1 + t] = lg[t];
  }
  if (r == NTOK - 1) {
#pragma unroll
    for (int t = 0; t < 34; ++t) out[1 + (size_t)(NTOK + 1) * 34 + t] = lg[t];
  }
  const size_t L2 = 1 + (size_t)(NTOK + 2) * 34;
  out[L2 + 1 + r] = (float)lab;
  if (r == 0) out[L2] = (float)lab;
  if (r == NTOK - 1) out[L2 + NTOK + 1] = (float)lab;
  // losses (static-index via selects; no scratch spill)
  float valid = (lab != pad) ? 1.f : 0.f;
  float sy = 0.f, pml_lab = 0.f, pml_pred = 0.f, so = -1e30f;
#pragma unroll
  for (int t = 0; t < 34; ++t) {
    bool il = (t == lab), ip = (t == pidx);
    sy = il ? lg[t] : sy;
    pml_lab = il ? p[34 + t] : pml_lab;
    pml_pred = ip ? p[34 + t] : pml_pred;
    so = fmaxf(so, il ? -1e30f : lg[t]);
  }
  float hl = fmaxf(0.f, 1.f + so - sy) * valid;
  float se = 0.f;
#pragma unroll
  for (int t = 0; t < 34; ++t) se += expf(lg[t] - best);
  float nll = (best + logf(se) - sy) * valid;
  float elab = pml_lab + tds * gmls[lab] + cml0s[lab];
  float epred = pml_pred + tds * gmls[pidx] + cml0s[pidx];
  float ed = elab - epred;
  pred[r] = pidx;
  if (s == 126) { atomicAdd(&hist[lab], 1); atomicAdd(&hist[68 + pidx], 1); }
  if (s == 127) { atomicAdd(&hist[34 + lab], 1); atomicAdd(&hist[102 + pidx], 1); }
  float vals[4] = { hl, nll, ed, valid };
#pragma unroll
  for (int j = 0; j < 4; ++j) {
    rb[s] = vals[j]; __syncthreads();
    for (int w = 64; w >= 1; w >>= 1) {
      if (s < w) rb[s] += rb[s + w];
      __syncthreads();
    }
    if (s == 0) atomicAdd(&accs[j], rb[0]);
    __syncthreads();
  }
}

// ---------------- K8: ste ----------------
__global__ __launch_bounds__(256) void k_ste(
    const float* __restrict__ x, const float* __restrict__ td,
    const int* __restrict__ pred, const int* __restrict__ padp,
    const float* __restrict__ xsum, const float* __restrict__ z,
    const float* __restrict__ linb, float* __restrict__ out) {
  int n = blockIdx.x, tid = threadIdx.x;
  __shared__ int bad[128];
  __shared__ float rb[256];
  int pad = padp[0];
  float tdv = 0.f; float good = 0.f; int isbad = 0;
  if (tid < 128) {
    int pd = pred[n * 128 + tid];
    isbad = (pd == pad);
    bad[tid] = isbad;
    if (!isbad) { tdv = td[n * 128 + tid]; good = 1.f; }
  }
  rb[tid] = tdv; __syncthreads();
  for (int w = 128; w >= 1; w >>= 1) { if (tid < w) rb[tid] += rb[tid + w]; __syncthreads(); }
  float tdm = rb[0]; __syncthreads();
  rb[tid] = good; __syncthreads();
  for (int w = 128; w >= 1; w >>= 1) { if (tid < w) rb[tid] += rb[tid + w]; __syncthreads(); }
  int cnt = (int)(rb[0] + 0.5f);
  __syncthreads();
  float a0 = xsum[n * 768 + tid], a1 = xsum[n * 768 + tid + 256], a2 = xsum[n * 768 + tid + 512];
  const float* xb = x + (size_t)n * 128 * 768;
  for (int s = 0; s < 128; ++s) {
    if (bad[s]) {
      a0 -= xb[s * 768 + tid]; a1 -= xb[s * 768 + tid + 256]; a2 -= xb[s * 768 + tid + 512];
    }
  }
  const size_t L3 = 1 + (size_t)(NTOK + 2) * 34 + (NTOK + 2);
  float fc = (float)cnt;
  float accs3[3] = { a0, a1, a2 };
#pragma unroll
  for (int i = 0; i < 3; ++i) {
    int h = tid + i * 256;
    float val = 0.f;
    if (cnt > 0) val = (accs3[i] + tdm * z[n * 768 + h] + fc * linb[h]) / fc;
    out[L3 + (size_t)n * 768 + h] = val;
  }
}

// ---------------- K9: final scalar ----------------
__global__ __launch_bounds__(256) void k_loss(
    const float* __restrict__ accs, const int* __restrict__ hist,
    const float* __restrict__ matlab, float* __restrict__ out) {
  int tid = threadIdx.x;
  __shared__ float rb[256];
  float v = 0.f;
  for (int i = tid; i < 1156; i += 256) {
    int t = i / 34, u = i - t * 34;
    v += ((float)(hist[t] * hist[34 + u]) - (float)(hist[68 + t] * hist[102 + u])) * matlab[i];
  }
  rb[tid] = v; __syncthreads();
  for (int w = 128; w >= 1; w >>= 1) { if (tid < w) rb[tid] += rb[tid + w]; __syncthreads(); }
  if (tid == 0) {
    float pair = rb[0];
    float nv = fmaxf(accs[3], 1.f);
    float hinge = accs[0] / nv;
    float ce = accs[1] / nv;
    float lte = fmaxf(0.f, hinge + accs[2] + pair);
    out[0] = lte + 0.5f * ce;
  }
}

extern "C" void kernel_launch(void* const* d_in, const int* in_sizes, int n_in,
                              void* d_out, int out_size, void* d_ws, size_t ws_size,
                              hipStream_t stream) {
  const float* x      = (const float*)d_in[0];
  const int*   labels = (const int*)d_in[1];
  const int*   padp   = (const int*)d_in[4];
  const float* Ww     = (const float*)d_in[6];
  const float* Wb     = (const float*)d_in[7];
  const float* vw     = (const float*)d_in[8];
  const float* vb     = (const float*)d_in[9];
  const float* clsw   = (const float*)d_in[10];
  const float* clsb   = (const float*)d_in[11];
  const float* matl   = (const float*)d_in[12];
  const float* matlab = (const float*)d_in[13];
  const float* linw   = (const float*)d_in[14];
  const float* linb   = (const float*)d_in[15];
  char* ws = (char*)d_ws;
  float* out = (float*)d_out;

  float*          sscore = (float*)(ws + OFF_SC);
  float*          accp   = (float*)(ws + OFF_ACC);
  int*            histp  = (int*)(ws + OFF_HIST);
  unsigned short* wbT    = (unsigned short*)(ws + OFF_WBT);
  float*          lsum   = (float*)(ws + OFF_LSUM);
  float*          bcat   = (float*)(ws + OFF_BCAT);
  float*          c0p    = (float*)(ws + OFF_C0);
  float*          cml0p  = (float*)(ws + OFF_CML0);
  float*          tdp    = (float*)(ws + OFF_TD);
  float*          headp  = (float*)(ws + OFF_HEAD);
  float*          xsump  = (float*)(ws + OFF_XSUM);
  float*          zp     = (float*)(ws + OFF_Z);
  float*          gp     = (float*)(ws + OFF_G);
  float*          gmlp   = (float*)(ws + OFF_GML);
  int*            predp  = (int*)(ws + OFF_PRED);
  float*          Pp     = (float*)(ws + OFF_P);

  hipMemsetAsync(ws, 0, ZERO_BYTES, stream);
  k_prep<<<4813, 256, 0, stream>>>(Ww, linw, clsw, matl, linb, clsb, wbT, lsum, bcat, c0p, cml0p);
  k_score<<<dim3(512, 12), 256, 0, stream>>>(x, wbT, Wb, vw, sscore);
  k_softmax_head<<<512, 256, 0, stream>>>(x, sscore, vb, tdp, headp, xsump);
  k_zgemm<<<128, 256, 0, stream>>>(headp, lsum, zp);
  k_gproj<<<512, 128, 0, stream>>>(zp, clsw, matl, gp, gmlp);
  k_pgemm<<<512, 256, 0, stream>>>(x, bcat, Pp);
  k_final<<<512, 128, 0, stream>>>(Pp, tdp, labels, padp, gp, gmlp, c0p, cml0p, out, predp, accp, histp);
  k_ste<<<512, 256, 0, stream>>>(x, tdp, predp, padp, xsump, zp, linb, out);
  k_loss<<<1, 256, 0, stream>>>(accp, histp, matlab, out);
}